// Round 6
// baseline (748.466 us; speedup 1.0000x reference)
//
#include <hip/hip_runtime.h>
#include <hip/hip_bf16.h>
#include <hip/hip_cooperative_groups.h>

namespace cg = cooperative_groups;

// Problem constants: B=16, T=8192, M=P=128, N2=128. Chunks: 64 per batch, L=128.
#define LCH 128
#define NCH 64
#define NCHUNKS 1024   // 16*64
#define GRID 512       // cooperative grid; 2 rounds of 512 chunks

typedef __attribute__((ext_vector_type(8))) short short8v;
typedef __attribute__((ext_vector_type(4))) short short4v;
typedef __attribute__((ext_vector_type(4))) float f32x4;

// ws layout (float2 offsets)
#define W2_LDINV 0          // [128 r][128 n]  Ld^{-(r+1)}
#define W2_LDP   16384      // [128 r][128 n]  Ld^{r+1}
#define W2_E     32768      // [1024 g][128 n]
#define W2_CIN   163840     // [1024 g][128 n]  (fallback path only)
#define W2_LDLP  163840     // [64 k][128 n]   Ldl^k = Ld^{128k}  (coop path; aliases CIN)
#define WS_WPACK_BYTE  (589824 * 4)         // 32768 bf16 (64 KB): [ntile16][ks4][lane64][j8]
#define WS_CCPACK_BYTE (589824 * 4 + 65536) // 32768 bf16: [ptile8][ks8][lane64][j8]

// bus LDS layout (k-blocked): byte(s, n') = (s>>3)*4096 + n'*16 + (s&7)*2
#define BUS_BYTE(s, np) ((((s) >> 3) * 4096) + ((np) * 16) + (((s) & 7) * 2))

__device__ inline unsigned short f2bf(float f) {
    union { __hip_bfloat16 h; unsigned short u; } v;
    v.h = __float2bfloat16(f);
    return v.u;
}
__device__ inline short4v pack4(float a, float b, float c, float d) {
    union { __hip_bfloat162 h2[2]; short4v s4; } pk;
    pk.h2[0] = __float22bfloat162_rn(make_float2(a, b));
    pk.h2[1] = __float22bfloat162_rn(make_float2(c, d));
    return pk.s4;
}

// ---------------- k0a: power tables (f64 exact) ----------------
// blocks 0..127: Ldinv[r], Ldp[r]. blocks 128..191: Ldl^(r-128).
__global__ void k0_pows(const float* __restrict__ lp, const float* __restrict__ delta,
                        float2* __restrict__ ws2) {
    const int r = blockIdx.x;
    const int tid = threadIdx.x;
    const int n = tid & 127;
    const double d = (double)delta[0];
    const double lre = -exp((double)lp[n]);
    const double lim = (double)lp[128 + n];
    if (r < 128) {
        const double kk = (double)(r + 1) * d;
        if (tid < 128) {
            const double mag = exp(-lre * kk);
            ws2[W2_LDINV + r * 128 + n] = make_float2((float)(mag * cos(lim * kk)),
                                                      (float)(-mag * sin(lim * kk)));
        } else {
            const double mag = exp(lre * kk);
            ws2[W2_LDP + r * 128 + n] = make_float2((float)(mag * cos(lim * kk)),
                                                    (float)(mag * sin(lim * kk)));
        }
    } else if (tid < 128) {
        const int k = r - 128;                       // 0..63
        const double kk = (double)k * d * (double)LCH;
        const double mag = exp(lre * kk);
        ws2[W2_LDLP + k * 128 + n] = make_float2((float)(mag * cos(lim * kk)),
                                                 (float)(mag * sin(lim * kk)));
    }
}

// ---------------- k0b: pack W = Bd^T as B-fragments ----------------
__global__ void k0_wpack(const float* __restrict__ lp, const float* __restrict__ bp,
                         const float* __restrict__ delta, unsigned short* __restrict__ wpack) {
    const int gid = blockIdx.x * 512 + threadIdx.x;    // 0..32767
    const int j = gid & 7;
    const int lane = (gid >> 3) & 63;
    const int ks = (gid >> 9) & 3;
    const int ntile = gid >> 11;
    const int np = ntile * 16 + (lane & 15);
    const int m = ks * 32 + ((lane >> 4) & 3) * 8 + j;
    const int n = np & 127;
    const double d = (double)delta[0];
    const double lre = -exp((double)lp[n]);
    const double lim = (double)lp[128 + n];
    const double er = exp(lre * d);
    const double ldr = er * cos(lim * d), ldi = er * sin(lim * d);
    const double nr = ldr - 1.0, ni = ldi;
    const double den = lre * lre + lim * lim;
    const double cr = (nr * lre + ni * lim) / den;
    const double ci = (ni * lre - nr * lim) / den;
    const double br = (double)bp[n * 128 + m];
    const double bi = (double)bp[16384 + n * 128 + m];
    const double v = (np < 128) ? (cr * br - ci * bi) : (cr * bi + ci * br);
    wpack[gid] = f2bf((float)v);
}

// ---------------- k0c: pack CC (K=256, re/im interleaved along k) ----------------
__global__ void k0_cpack(const float* __restrict__ cp, unsigned short* __restrict__ ccpack) {
    const int gid = blockIdx.x * 512 + threadIdx.x;    // 0..32767
    const int j = gid & 7;
    const int lane = (gid >> 3) & 63;
    const int ks = (gid >> 9) & 7;
    const int ptile = gid >> 12;
    const int p = ptile * 16 + (lane & 15);
    const int k = ks * 32 + ((lane >> 4) & 3) * 8 + j;
    const int n = k >> 1;
    const float v = ((k & 1) == 0) ? 2.0f * cp[p * 128 + n] : -2.0f * cp[16384 + p * 128 + n];
    ccpack[gid] = f2bf(v);
}

// ---------------- shared helper: stage u chunk -> LDS bf16 [t][m], XOR swizzle ----------------
__device__ inline void stage_u(const float* __restrict__ uchunk, unsigned short* lds_u) {
    const float4* uf = (const float4*)uchunk;
    const int tid = threadIdx.x;
#pragma unroll
    for (int it = 0; it < 8; ++it) {
        const int f4 = it * 512 + tid;
        const float4 v = uf[f4];
        const int t = f4 >> 5;
        const int m = (f4 & 31) * 4;
        const int byte = (t * 256 + m * 2) ^ ((t & 7) << 4);
        *(short4v*)((char*)lds_u + byte) = pack4(v.x, v.y, v.z, v.w);
    }
}

// GEMM1 halves + Ldinv scale + bus write (shared by kmain / fallback k3)
__device__ inline void gemm1_to_bus(unsigned short* lds, const float2* ws2,
                                    const unsigned short* wpack,
                                    int w, int lane, int tl, int gq, int n) {
    const short8v* wp = (const short8v*)wpack;
#pragma unroll
    for (int hh = 0; hh < 2; ++hh) {
        const int h = 1 - hh;
        f32x4 acc[4][2];
#pragma unroll
        for (int i = 0; i < 4; ++i) { acc[i][0] = (f32x4)0.f; acc[i][1] = (f32x4)0.f; }
        __builtin_amdgcn_s_setprio(1);
#pragma unroll
        for (int ks = 0; ks < 4; ++ks) {
            const short8v b0 = wp[(w * 4 + ks) * 64 + lane];
            const short8v b1 = wp[((8 + w) * 4 + ks) * 64 + lane];
#pragma unroll
            for (int tt2 = 0; tt2 < 4; ++tt2) {
                const int t = (h * 4 + tt2) * 16 + tl;
                const int byte = (t * 256 + (ks * 32 + gq * 8) * 2) ^ ((t & 7) << 4);
                const short8v a = *(const short8v*)((const char*)lds + byte);
                acc[tt2][0] = __builtin_amdgcn_mfma_f32_16x16x32_bf16(a, b0, acc[tt2][0], 0, 0, 0);
                acc[tt2][1] = __builtin_amdgcn_mfma_f32_16x16x32_bf16(a, b1, acc[tt2][1], 0, 0, 0);
            }
        }
        __builtin_amdgcn_s_setprio(0);
        __builtin_amdgcn_sched_barrier(0);
        if (h == 0) __syncthreads();   // all waves done reading u; s<64 bus may overwrite it
#pragma unroll
        for (int tt2 = 0; tt2 < 4; ++tt2) {
            float vr[4], vi[4];
#pragma unroll
            for (int reg = 0; reg < 4; ++reg) {
                const int r = (h * 4 + tt2) * 16 + gq * 4 + reg;
                const float2 li = ws2[W2_LDINV + r * 128 + n];
                const float br = acc[tt2][0][reg], bi = acc[tt2][1][reg];
                vr[reg] = li.x * br - li.y * bi;
                vi[reg] = li.x * bi + li.y * br;
            }
            const int s0 = (h * 4 + tt2) * 16 + gq * 4;
            const int rowr = w * 16 + tl;
            const int rowi = 128 + rowr;
            *(short4v*)((char*)lds + BUS_BYTE(s0, rowr)) = pack4(vr[0], vr[1], vr[2], vr[3]);
            *(short4v*)((char*)lds + BUS_BYTE(s0, rowi)) = pack4(vi[0], vi[1], vi[2], vi[3]);
        }
        __builtin_amdgcn_sched_barrier(0);
    }
}

// GEMM2 tri-cumsum (wave-private bus rows)
__device__ inline void gemm2_cumsum(const unsigned short* lds, int w, int tl, int gq,
                                    f32x4 z[8][2]) {
    short8v ONES, D0, D1;
#pragma unroll
    for (int j = 0; j < 8; ++j) {
        const int sl = gq * 8 + j;
        ONES[j] = (short)0x3F80;
        D0[j] = (sl <= tl) ? (short)0x3F80 : (short)0;
        D1[j] = (sl <= tl + 16) ? (short)0x3F80 : (short)0;
    }
#pragma unroll
    for (int i = 0; i < 8; ++i) { z[i][0] = (f32x4)0.f; z[i][1] = (f32x4)0.f; }
#pragma unroll
    for (int ks = 0; ks < 4; ++ks) {
        const int sb = ks * 32 + gq * 8;                 // frag k-base, (sb&7)==0
        const int rowr = w * 16 + tl;
        const int rowi = 128 + rowr;
        const short8v b0 = *(const short8v*)((const char*)lds + BUS_BYTE(sb, rowr));
        const short8v b1 = *(const short8v*)((const char*)lds + BUS_BYTE(sb, rowi));
#pragma unroll
        for (int tt = 0; tt < 8; ++tt) {
            if (tt < 2 * ks) continue;                   // zero block
            const short8v a = (tt == 2 * ks) ? D0 : ((tt == 2 * ks + 1) ? D1 : ONES);
            z[tt][0] = __builtin_amdgcn_mfma_f32_16x16x32_bf16(a, b0, z[tt][0], 0, 0, 0);
            z[tt][1] = __builtin_amdgcn_mfma_f32_16x16x32_bf16(a, b1, z[tt][1], 0, 0, 0);
        }
    }
}

// x write + GEMM3 + y store (shared tail)
__device__ inline void tail_x_gemm3(unsigned short* lds, const float2* ws2,
                                    const unsigned short* ccpack, float* y,
                                    int b, int c, int w, int lane, int tl, int gq, int n,
                                    const f32x4 z[8][2], float cr, float ci) {
#pragma unroll
    for (int tt = 0; tt < 8; ++tt) {
#pragma unroll
        for (int reg = 0; reg < 4; ++reg) {
            const int r = tt * 16 + gq * 4 + reg;
            const float2 ld = ws2[W2_LDP + r * 128 + n];
            const float zr = z[tt][0][reg] + cr;
            const float zi = z[tt][1][reg] + ci;
            const float xr = ld.x * zr - ld.y * zi;
            const float xi = ld.x * zi + ld.y * zr;
            union { __hip_bfloat162 h2; unsigned uu; } pk;
            pk.h2 = __float22bfloat162_rn(make_float2(xr, xi));
            const int byte = (r * 512 + n * 4) ^ ((r & 7) << 4);
            *(unsigned*)((char*)lds + byte) = pk.uu;
        }
    }
    __syncthreads();
    const short8v* cc8 = (const short8v*)ccpack;
    f32x4 yac[8];
#pragma unroll
    for (int i = 0; i < 8; ++i) yac[i] = (f32x4)0.f;
    __builtin_amdgcn_s_setprio(1);
#pragma unroll
    for (int ks = 0; ks < 8; ++ks) {
        const short8v bfrg = cc8[(w * 8 + ks) * 64 + lane];
#pragma unroll
        for (int tt = 0; tt < 8; ++tt) {
            const int t = tt * 16 + tl;
            const int byte = (t * 512 + (ks * 32 + gq * 8) * 2) ^ ((t & 7) << 4);
            const short8v a = *(const short8v*)((const char*)lds + byte);
            yac[tt] = __builtin_amdgcn_mfma_f32_16x16x32_bf16(a, bfrg, yac[tt], 0, 0, 0);
        }
    }
    __builtin_amdgcn_s_setprio(0);
    const int p = w * 16 + tl;
    float* yrow = y + (size_t)(b * 8192 + c * 128) * 128;
#pragma unroll
    for (int tt = 0; tt < 8; ++tt) {
#pragma unroll
        for (int reg = 0; reg < 4; ++reg) {
            const int t = tt * 16 + gq * 4 + reg;
            yrow[t * 128 + p] = yac[tt][reg];
        }
    }
}

// ================= cooperative main kernel =================
__global__ __launch_bounds__(512, 4) void kmain(const float* __restrict__ u,
                                                float2* __restrict__ ws2,
                                                const unsigned short* __restrict__ wpack,
                                                const unsigned short* __restrict__ ccpack,
                                                float* __restrict__ y) {
    __shared__ unsigned short lds[32768];     // 64 KB
    cg::grid_group grid = cg::this_grid();
    const int tid = threadIdx.x;
    const int lane = tid & 63;
    const int w = tid >> 6;
    const int tl = lane & 15;
    const int gq = (lane >> 4) & 3;
    const int n = w * 16 + tl;

    for (int rd = 0; rd < 2; ++rd) {
        const int g = rd * GRID + blockIdx.x;
        const int b = g >> 6;
        const int c = g & 63;

        if (rd) __syncthreads();       // previous round's GEMM3 LDS reads retired
        stage_u(u + (size_t)(b * 8192 + c * 128) * 128, lds);
        __syncthreads();

        gemm1_to_bus(lds, ws2, wpack, w, lane, tl, gq, n);

        f32x4 z[8][2];
        gemm2_cumsum(lds, w, tl, gq, z);

        // E[g][n] = Ld^128 * z[127][n]  (row 127 lives in z[7][*][3] on lanes gq==3)
        if (gq == 3) {
            const float er = z[7][0][3], ei = z[7][1][3];
            const float2 ld = ws2[W2_LDP + 127 * 128 + n];
            ws2[W2_E + g * 128 + n] = make_float2(ld.x * er - ld.y * ei,
                                                  ld.x * ei + ld.y * er);
        }
        __threadfence();
        grid.sync();

        // carry[c] = sum_{j<c} Ldl^(c-1-j) * E[b][j]  — independent terms, pipelined
        float cr = 0.f, ci = 0.f;
        for (int j = 0; j < c; ++j) {
            const float2 e = ws2[W2_E + (b * NCH + j) * 128 + n];
            const float2 pw = ws2[W2_LDLP + (c - 1 - j) * 128 + n];
            cr += pw.x * e.x - pw.y * e.y;
            ci += pw.x * e.y + pw.y * e.x;
        }

        tail_x_gemm3(lds, ws2, ccpack, y, b, c, w, lane, tl, gq, n, z, cr, ci);
    }
}

// ================= fallback path (R4 three-kernel) =================
__global__ __launch_bounds__(512, 4) void k1_end(const float* __restrict__ u,
                                                 float2* __restrict__ ws2,
                                                 const unsigned short* __restrict__ wpack) {
    __shared__ unsigned short lds_u[16384];   // 32 KB
    const int tid = threadIdx.x;
    const int lane = tid & 63;
    const int w = tid >> 6;
    const int tl = lane & 15;
    const int gq = (lane >> 4) & 3;
    const int g = blockIdx.x;
    const int b = g >> 6;
    const int c = g & 63;
    const int n = w * 16 + tl;
    stage_u(u + (size_t)(b * 8192 + c * 128) * 128, lds_u);
    __syncthreads();
    const short8v* wp = (const short8v*)wpack;
    float er = 0.f, ei = 0.f;
#pragma unroll
    for (int h = 0; h < 2; ++h) {
        f32x4 acc[4][2];
#pragma unroll
        for (int i = 0; i < 4; ++i) { acc[i][0] = (f32x4)0.f; acc[i][1] = (f32x4)0.f; }
        __builtin_amdgcn_s_setprio(1);
#pragma unroll
        for (int ks = 0; ks < 4; ++ks) {
            const short8v b0 = wp[(w * 4 + ks) * 64 + lane];
            const short8v b1 = wp[((8 + w) * 4 + ks) * 64 + lane];
#pragma unroll
            for (int tt2 = 0; tt2 < 4; ++tt2) {
                const int t = (h * 4 + tt2) * 16 + tl;
                const int byte = (t * 256 + (ks * 32 + gq * 8) * 2) ^ ((t & 7) << 4);
                const short8v a = *(const short8v*)((const char*)lds_u + byte);
                acc[tt2][0] = __builtin_amdgcn_mfma_f32_16x16x32_bf16(a, b0, acc[tt2][0], 0, 0, 0);
                acc[tt2][1] = __builtin_amdgcn_mfma_f32_16x16x32_bf16(a, b1, acc[tt2][1], 0, 0, 0);
            }
        }
        __builtin_amdgcn_s_setprio(0);
        __builtin_amdgcn_sched_barrier(0);
#pragma unroll
        for (int tt2 = 0; tt2 < 4; ++tt2) {
#pragma unroll
            for (int reg = 0; reg < 4; ++reg) {
                const int r = (h * 4 + tt2) * 16 + gq * 4 + reg;
                const float2 li = ws2[W2_LDINV + r * 128 + n];
                const float br = acc[tt2][0][reg], bi = acc[tt2][1][reg];
                er += li.x * br - li.y * bi;
                ei += li.x * bi + li.y * br;
            }
        }
        __builtin_amdgcn_sched_barrier(0);
    }
    er += __shfl_xor(er, 16); ei += __shfl_xor(ei, 16);
    er += __shfl_xor(er, 32); ei += __shfl_xor(ei, 32);
    const float2 ld = ws2[W2_LDP + 127 * 128 + n];
    if (lane < 16) {
        ws2[W2_E + g * 128 + n] = make_float2(ld.x * er - ld.y * ei,
                                              ld.x * ei + ld.y * er);
    }
}

__global__ void k2_carry(float2* __restrict__ ws2) {
    const int idx = blockIdx.x * 256 + threadIdx.x;   // 0..2047
    const int b = idx >> 7;
    const int n = idx & 127;
    const float2 l = ws2[W2_LDP + 127 * 128 + n];
    float cr = 0.f, ci = 0.f;
    for (int c = 0; c < NCH; ++c) {
        const int o = (b * NCH + c) * 128 + n;
        ws2[W2_CIN + o] = make_float2(cr, ci);
        const float2 e = ws2[W2_E + o];
        const float nr = fmaf(l.x, cr, fmaf(-l.y, ci, e.x));
        const float ni = fmaf(l.x, ci, fmaf(l.y, cr, e.y));
        cr = nr; ci = ni;
    }
}

__global__ __launch_bounds__(512, 4) void k3_main(const float* __restrict__ u,
                                                  const float2* __restrict__ ws2,
                                                  const unsigned short* __restrict__ wpack,
                                                  const unsigned short* __restrict__ ccpack,
                                                  float* __restrict__ y) {
    __shared__ unsigned short lds[32768];     // 64 KB
    const int tid = threadIdx.x;
    const int lane = tid & 63;
    const int w = tid >> 6;
    const int tl = lane & 15;
    const int gq = (lane >> 4) & 3;
    const int g = blockIdx.x;
    const int b = g >> 6;
    const int c = g & 63;
    const int n = w * 16 + tl;

    stage_u(u + (size_t)(b * 8192 + c * 128) * 128, lds);
    __syncthreads();
    gemm1_to_bus(lds, ws2, wpack, w, lane, tl, gq, n);
    f32x4 z[8][2];
    gemm2_cumsum(lds, w, tl, gq, z);
    __syncthreads();
    const float2 cin = ws2[W2_CIN + g * 128 + n];
    tail_x_gemm3(lds, ws2, ccpack, y, b, c, w, lane, tl, gq, n, z, cin.x, cin.y);
}

extern "C" void kernel_launch(void* const* d_in, const int* in_sizes, int n_in,
                              void* d_out, int out_size, void* d_ws, size_t ws_size,
                              hipStream_t stream) {
    const float* u     = (const float*)d_in[0];
    const float* lp    = (const float*)d_in[1];
    const float* bp    = (const float*)d_in[2];
    const float* cp    = (const float*)d_in[3];
    const float* delta = (const float*)d_in[4];
    float* y  = (float*)d_out;
    float2* ws2 = (float2*)d_ws;
    unsigned short* wpack  = (unsigned short*)((char*)d_ws + WS_WPACK_BYTE);
    unsigned short* ccpack = (unsigned short*)((char*)d_ws + WS_CCPACK_BYTE);

    k0_pows <<<192, 256, 0, stream>>>(lp, delta, ws2);
    k0_wpack<<<64, 512, 0, stream>>>(lp, bp, delta, wpack);
    k0_cpack<<<64, 512, 0, stream>>>(cp, ccpack);

    const float* u_a = u; float2* ws2_a = ws2;
    const unsigned short* wp_a = wpack; const unsigned short* cc_a = ccpack;
    float* y_a = y;
    void* args[] = {(void*)&u_a, (void*)&ws2_a, (void*)&wp_a, (void*)&cc_a, (void*)&y_a};
    hipError_t err = hipLaunchCooperativeKernel((const void*)kmain, dim3(GRID), dim3(512),
                                                args, 0, stream);
    if (err != hipSuccess) {
        // fallback: non-cooperative three-pass path (R4)
        k1_end  <<<NCHUNKS, 512, 0, stream>>>(u, ws2, wpack);
        k2_carry<<<8, 256, 0, stream>>>(ws2);
        k3_main <<<NCHUNKS, 512, 0, stream>>>(u, ws2, wpack, ccpack, y);
    }
}

// Round 8
// 535.510 us; speedup vs baseline: 1.3977x; 1.3977x over previous
//
#include <hip/hip_runtime.h>
#include <hip/hip_bf16.h>

// Problem constants: B=16, T=8192, M=P=128, N2=128. Chunks: 64 per batch, L=128.
#define LCH 128
#define NCH 64
#define GRID 512       // persistent grid; 2 rounds of 512 chunks (batches 0-7, then 8-15)

typedef __attribute__((ext_vector_type(8))) short short8v;
typedef __attribute__((ext_vector_type(4))) short short4v;
typedef __attribute__((ext_vector_type(4))) float f32x4;

// ws layout (float2 offsets)
#define W2_LDINV 0          // [128 r][128 n]  Ld^{-(r+1)}
#define W2_LDP   16384      // [128 r][128 n]  Ld^{r+1}
#define W2_E     32768      // [1024 g][128 n]
#define W2_LDLP  163840     // [64 k][128 n]   Ldl^k = Ld^{128k}
#define W2_CNT   172032     // 16 uint arrival counters (one per batch)
#define WS_WPACK_BYTE  (589824 * 4)         // 32768 bf16 (64 KB): [ntile16][ks4][lane64][j8]
#define WS_CCPACK_BYTE (589824 * 4 + 65536) // 32768 bf16: [ptile8][ks8][lane64][j8]

// bus LDS layout (k-blocked): byte(s, n') = (s>>3)*4096 + n'*16 + (s&7)*2
#define BUS_BYTE(s, np) ((((s) >> 3) * 4096) + ((np) * 16) + (((s) & 7) * 2))

__device__ inline unsigned short f2bf(float f) {
    union { __hip_bfloat16 h; unsigned short u; } v;
    v.h = __float2bfloat16(f);
    return v.u;
}
__device__ inline short4v pack4(float a, float b, float c, float d) {
    union { __hip_bfloat162 h2[2]; short4v s4; } pk;
    pk.h2[0] = __float22bfloat162_rn(make_float2(a, b));
    pk.h2[1] = __float22bfloat162_rn(make_float2(c, d));
    return pk.s4;
}

// cross-XCD-coherent 8-byte data movement (agent-scope atomics bypass the
// non-coherent per-XCD L2 path — same mechanism as the arrival counters,
// which R7 empirically validated; plain stores + fences did NOT work).
__device__ inline void coh_store_f2(float2* p, float2 v) {
    union { float2 f; unsigned long long u; } pk; pk.f = v;
    __hip_atomic_store((unsigned long long*)p, pk.u, __ATOMIC_RELAXED,
                       __HIP_MEMORY_SCOPE_AGENT);
}
__device__ inline float2 coh_load_f2(const float2* p) {
    union { float2 f; unsigned long long u; } pk;
    pk.u = __hip_atomic_load((const unsigned long long*)p, __ATOMIC_RELAXED,
                             __HIP_MEMORY_SCOPE_AGENT);
    return pk.f;
}

// ---------------- k0a: power tables (f64 exact) + counter reset ----------------
// blocks 0..127: Ldinv[r], Ldp[r]. blocks 128..191: Ldl^(r-128). block 128 zeroes counters.
__global__ void k0_pows(const float* __restrict__ lp, const float* __restrict__ delta,
                        float2* __restrict__ ws2) {
    const int r = blockIdx.x;
    const int tid = threadIdx.x;
    const int n = tid & 127;
    const double d = (double)delta[0];
    const double lre = -exp((double)lp[n]);
    const double lim = (double)lp[128 + n];
    if (r < 128) {
        const double kk = (double)(r + 1) * d;
        if (tid < 128) {
            const double mag = exp(-lre * kk);
            ws2[W2_LDINV + r * 128 + n] = make_float2((float)(mag * cos(lim * kk)),
                                                      (float)(-mag * sin(lim * kk)));
        } else {
            const double mag = exp(lre * kk);
            ws2[W2_LDP + r * 128 + n] = make_float2((float)(mag * cos(lim * kk)),
                                                    (float)(mag * sin(lim * kk)));
        }
    } else {
        if (tid < 128) {
            const int k = r - 128;                       // 0..63
            const double kk = (double)k * d * (double)LCH;
            const double mag = exp(lre * kk);
            ws2[W2_LDLP + k * 128 + n] = make_float2((float)(mag * cos(lim * kk)),
                                                     (float)(mag * sin(lim * kk)));
        } else if (r == 128 && tid < 144) {
            // reset the 16 per-batch arrival counters every launch (graph-replay safe)
            __hip_atomic_store(&((unsigned*)(ws2 + W2_CNT))[tid - 128], 0u,
                               __ATOMIC_RELAXED, __HIP_MEMORY_SCOPE_AGENT);
        }
    }
}

// ---------------- k0b: pack W = Bd^T as B-fragments ----------------
__global__ void k0_wpack(const float* __restrict__ lp, const float* __restrict__ bp,
                         const float* __restrict__ delta, unsigned short* __restrict__ wpack) {
    const int gid = blockIdx.x * 512 + threadIdx.x;    // 0..32767
    const int j = gid & 7;
    const int lane = (gid >> 3) & 63;
    const int ks = (gid >> 9) & 3;
    const int ntile = gid >> 11;
    const int np = ntile * 16 + (lane & 15);
    const int m = ks * 32 + ((lane >> 4) & 3) * 8 + j;
    const int n = np & 127;
    const double d = (double)delta[0];
    const double lre = -exp((double)lp[n]);
    const double lim = (double)lp[128 + n];
    const double er = exp(lre * d);
    const double ldr = er * cos(lim * d), ldi = er * sin(lim * d);
    const double nr = ldr - 1.0, ni = ldi;
    const double den = lre * lre + lim * lim;
    const double cr = (nr * lre + ni * lim) / den;
    const double ci = (ni * lre - nr * lim) / den;
    const double br = (double)bp[n * 128 + m];
    const double bi = (double)bp[16384 + n * 128 + m];
    const double v = (np < 128) ? (cr * br - ci * bi) : (cr * bi + ci * br);
    wpack[gid] = f2bf((float)v);
}

// ---------------- k0c: pack CC (K=256, re/im interleaved along k) ----------------
__global__ void k0_cpack(const float* __restrict__ cp, unsigned short* __restrict__ ccpack) {
    const int gid = blockIdx.x * 512 + threadIdx.x;    // 0..32767
    const int j = gid & 7;
    const int lane = (gid >> 3) & 63;
    const int ks = (gid >> 9) & 7;
    const int ptile = gid >> 12;
    const int p = ptile * 16 + (lane & 15);
    const int k = ks * 32 + ((lane >> 4) & 3) * 8 + j;
    const int n = k >> 1;
    const float v = ((k & 1) == 0) ? 2.0f * cp[p * 128 + n] : -2.0f * cp[16384 + p * 128 + n];
    ccpack[gid] = f2bf(v);
}

// ---------------- shared helper: stage u chunk -> LDS bf16 [t][m], XOR swizzle ----------------
__device__ inline void stage_u(const float* __restrict__ uchunk, unsigned short* lds_u) {
    const float4* uf = (const float4*)uchunk;
    const int tid = threadIdx.x;
#pragma unroll
    for (int it = 0; it < 8; ++it) {
        const int f4 = it * 512 + tid;
        const float4 v = uf[f4];
        const int t = f4 >> 5;
        const int m = (f4 & 31) * 4;
        const int byte = (t * 256 + m * 2) ^ ((t & 7) << 4);
        *(short4v*)((char*)lds_u + byte) = pack4(v.x, v.y, v.z, v.w);
    }
}

// GEMM1 halves + Ldinv scale + bus write
__device__ inline void gemm1_to_bus(unsigned short* lds, const float2* ws2,
                                    const unsigned short* wpack,
                                    int w, int lane, int tl, int gq, int n) {
    const short8v* wp = (const short8v*)wpack;
#pragma unroll
    for (int hh = 0; hh < 2; ++hh) {
        const int h = 1 - hh;
        f32x4 acc[4][2];
#pragma unroll
        for (int i = 0; i < 4; ++i) { acc[i][0] = (f32x4)0.f; acc[i][1] = (f32x4)0.f; }
        __builtin_amdgcn_s_setprio(1);
#pragma unroll
        for (int ks = 0; ks < 4; ++ks) {
            const short8v b0 = wp[(w * 4 + ks) * 64 + lane];
            const short8v b1 = wp[((8 + w) * 4 + ks) * 64 + lane];
#pragma unroll
            for (int tt2 = 0; tt2 < 4; ++tt2) {
                const int t = (h * 4 + tt2) * 16 + tl;
                const int byte = (t * 256 + (ks * 32 + gq * 8) * 2) ^ ((t & 7) << 4);
                const short8v a = *(const short8v*)((const char*)lds + byte);
                acc[tt2][0] = __builtin_amdgcn_mfma_f32_16x16x32_bf16(a, b0, acc[tt2][0], 0, 0, 0);
                acc[tt2][1] = __builtin_amdgcn_mfma_f32_16x16x32_bf16(a, b1, acc[tt2][1], 0, 0, 0);
            }
        }
        __builtin_amdgcn_s_setprio(0);
        __builtin_amdgcn_sched_barrier(0);
        if (h == 0) __syncthreads();   // all waves done reading u; s<64 bus may overwrite it
#pragma unroll
        for (int tt2 = 0; tt2 < 4; ++tt2) {
            float vr[4], vi[4];
#pragma unroll
            for (int reg = 0; reg < 4; ++reg) {
                const int r = (h * 4 + tt2) * 16 + gq * 4 + reg;
                const float2 li = ws2[W2_LDINV + r * 128 + n];
                const float br = acc[tt2][0][reg], bi = acc[tt2][1][reg];
                vr[reg] = li.x * br - li.y * bi;
                vi[reg] = li.x * bi + li.y * br;
            }
            const int s0 = (h * 4 + tt2) * 16 + gq * 4;
            const int rowr = w * 16 + tl;
            const int rowi = 128 + rowr;
            *(short4v*)((char*)lds + BUS_BYTE(s0, rowr)) = pack4(vr[0], vr[1], vr[2], vr[3]);
            *(short4v*)((char*)lds + BUS_BYTE(s0, rowi)) = pack4(vi[0], vi[1], vi[2], vi[3]);
        }
        __builtin_amdgcn_sched_barrier(0);
    }
}

// GEMM2 tri-cumsum (wave-private bus rows)
__device__ inline void gemm2_cumsum(const unsigned short* lds, int w, int tl, int gq,
                                    f32x4 z[8][2]) {
    short8v ONES, D0, D1;
#pragma unroll
    for (int j = 0; j < 8; ++j) {
        const int sl = gq * 8 + j;
        ONES[j] = (short)0x3F80;
        D0[j] = (sl <= tl) ? (short)0x3F80 : (short)0;
        D1[j] = (sl <= tl + 16) ? (short)0x3F80 : (short)0;
    }
#pragma unroll
    for (int i = 0; i < 8; ++i) { z[i][0] = (f32x4)0.f; z[i][1] = (f32x4)0.f; }
#pragma unroll
    for (int ks = 0; ks < 4; ++ks) {
        const int sb = ks * 32 + gq * 8;                 // frag k-base, (sb&7)==0
        const int rowr = w * 16 + tl;
        const int rowi = 128 + rowr;
        const short8v b0 = *(const short8v*)((const char*)lds + BUS_BYTE(sb, rowr));
        const short8v b1 = *(const short8v*)((const char*)lds + BUS_BYTE(sb, rowi));
#pragma unroll
        for (int tt = 0; tt < 8; ++tt) {
            if (tt < 2 * ks) continue;                   // zero block
            const short8v a = (tt == 2 * ks) ? D0 : ((tt == 2 * ks + 1) ? D1 : ONES);
            z[tt][0] = __builtin_amdgcn_mfma_f32_16x16x32_bf16(a, b0, z[tt][0], 0, 0, 0);
            z[tt][1] = __builtin_amdgcn_mfma_f32_16x16x32_bf16(a, b1, z[tt][1], 0, 0, 0);
        }
    }
}

// x write + GEMM3 + y store
__device__ inline void tail_x_gemm3(unsigned short* lds, const float2* ws2,
                                    const unsigned short* ccpack, float* y,
                                    int b, int c, int w, int lane, int tl, int gq, int n,
                                    const f32x4 z[8][2], float cr, float ci) {
#pragma unroll
    for (int tt = 0; tt < 8; ++tt) {
#pragma unroll
        for (int reg = 0; reg < 4; ++reg) {
            const int r = tt * 16 + gq * 4 + reg;
            const float2 ld = ws2[W2_LDP + r * 128 + n];
            const float zr = z[tt][0][reg] + cr;
            const float zi = z[tt][1][reg] + ci;
            const float xr = ld.x * zr - ld.y * zi;
            const float xi = ld.x * zi + ld.y * zr;
            union { __hip_bfloat162 h2; unsigned uu; } pk;
            pk.h2 = __float22bfloat162_rn(make_float2(xr, xi));
            const int byte = (r * 512 + n * 4) ^ ((r & 7) << 4);
            *(unsigned*)((char*)lds + byte) = pk.uu;
        }
    }
    __syncthreads();
    const short8v* cc8 = (const short8v*)ccpack;
    f32x4 yac[8];
#pragma unroll
    for (int i = 0; i < 8; ++i) yac[i] = (f32x4)0.f;
    __builtin_amdgcn_s_setprio(1);
#pragma unroll
    for (int ks = 0; ks < 8; ++ks) {
        const short8v bfrg = cc8[(w * 8 + ks) * 64 + lane];
#pragma unroll
        for (int tt = 0; tt < 8; ++tt) {
            const int t = tt * 16 + tl;
            const int byte = (t * 512 + (ks * 32 + gq * 8) * 2) ^ ((t & 7) << 4);
            const short8v a = *(const short8v*)((const char*)lds + byte);
            yac[tt] = __builtin_amdgcn_mfma_f32_16x16x32_bf16(a, bfrg, yac[tt], 0, 0, 0);
        }
    }
    __builtin_amdgcn_s_setprio(0);
    const int p = w * 16 + tl;
    float* yrow = y + (size_t)(b * 8192 + c * 128) * 128;
#pragma unroll
    for (int tt = 0; tt < 8; ++tt) {
#pragma unroll
        for (int reg = 0; reg < 4; ++reg) {
            const int t = tt * 16 + gq * 4 + reg;
            yrow[t * 128 + p] = yac[tt][reg];
        }
    }
}

// ================= fused persistent kernel with inline flag sync =================
// Round rd handles chunks g = rd*512 + blockIdx.x (batches 8rd..8rd+7).
// Per batch b, 64 producer blocks publish E[g] via AGENT-scope atomic stores
// (cross-XCD coherent) then bump cnt[b] (release); consumers spin (acquire)
// until cnt[b]==64, then carry = dot(Ldl powers, E) via AGENT-scope atomic loads.
// All 512 blocks co-resident (R6 cooperative launch validated the geometry);
// batches never span rounds -> no deadlock.
__global__ __launch_bounds__(512, 4) void kmain(const float* __restrict__ u,
                                                float2* __restrict__ ws2,
                                                const unsigned short* __restrict__ wpack,
                                                const unsigned short* __restrict__ ccpack,
                                                float* __restrict__ y) {
    __shared__ unsigned short lds[32768];     // 64 KB
    const int tid = threadIdx.x;
    const int lane = tid & 63;
    const int w = tid >> 6;
    const int tl = lane & 15;
    const int gq = (lane >> 4) & 3;
    const int n = w * 16 + tl;
    unsigned* cnt = (unsigned*)(ws2 + W2_CNT);

    for (int rd = 0; rd < 2; ++rd) {
        const int g = rd * GRID + (int)blockIdx.x;
        const int b = g >> 6;
        const int c = g & 63;

        if (rd) __syncthreads();       // previous round's GEMM3 LDS reads retired
        stage_u(u + (size_t)(b * 8192 + c * 128) * 128, lds);
        __syncthreads();

        gemm1_to_bus(lds, ws2, wpack, w, lane, tl, gq, n);

        f32x4 z[8][2];
        gemm2_cumsum(lds, w, tl, gq, z);

        // publish E[g][n] = Ld^128 * z[127][n]  (row 127 = z[7][*][3] on lanes gq==3)
        if (gq == 3) {
            const float er = z[7][0][3], ei = z[7][1][3];
            const float2 ld = ws2[W2_LDP + 127 * 128 + n];
            coh_store_f2(&ws2[W2_E + g * 128 + n],
                         make_float2(ld.x * er - ld.y * ei, ld.x * ei + ld.y * er));
        }
        __syncthreads();               // all waves' E stores drained (vmcnt0 at barrier)
        if (tid == 0) {
            __hip_atomic_fetch_add(&cnt[b], 1u, __ATOMIC_RELEASE, __HIP_MEMORY_SCOPE_AGENT);
        }

        // carry[c] = sum_{j<c} Ldl^(c-1-j) * E[b*64+j]
        float cr = 0.f, ci = 0.f;
        if (c > 0) {
            if (tid == 0) {
                while (__hip_atomic_load(&cnt[b], __ATOMIC_ACQUIRE,
                                         __HIP_MEMORY_SCOPE_AGENT) < (unsigned)NCH) {
                    __builtin_amdgcn_s_sleep(2);
                }
            }
            __syncthreads();
            for (int j = 0; j < c; ++j) {
                const float2 e = coh_load_f2(&ws2[W2_E + (b * NCH + j) * 128 + n]);
                const float2 pw = ws2[W2_LDLP + (c - 1 - j) * 128 + n];
                cr += pw.x * e.x - pw.y * e.y;
                ci += pw.x * e.y + pw.y * e.x;
            }
        }

        tail_x_gemm3(lds, ws2, ccpack, y, b, c, w, lane, tl, gq, n, z, cr, ci);
    }
}

extern "C" void kernel_launch(void* const* d_in, const int* in_sizes, int n_in,
                              void* d_out, int out_size, void* d_ws, size_t ws_size,
                              hipStream_t stream) {
    const float* u     = (const float*)d_in[0];
    const float* lp    = (const float*)d_in[1];
    const float* bp    = (const float*)d_in[2];
    const float* cp    = (const float*)d_in[3];
    const float* delta = (const float*)d_in[4];
    float* y  = (float*)d_out;
    float2* ws2 = (float2*)d_ws;
    unsigned short* wpack  = (unsigned short*)((char*)d_ws + WS_WPACK_BYTE);
    unsigned short* ccpack = (unsigned short*)((char*)d_ws + WS_CCPACK_BYTE);

    k0_pows <<<192, 256, 0, stream>>>(lp, delta, ws2);
    k0_wpack<<<64, 512, 0, stream>>>(lp, bp, delta, wpack);
    k0_cpack<<<64, 512, 0, stream>>>(cp, ccpack);
    kmain   <<<GRID, 512, 0, stream>>>(u, ws2, wpack, ccpack, y);
}